// Round 1
// baseline (276.144 us; speedup 1.0000x reference)
//
#include <hip/hip_runtime.h>
#include <stdint.h>

typedef unsigned short u16;
typedef __attribute__((ext_vector_type(8))) short bf16x8;   // 8 bf16 = 4 VGPRs (MFMA A/B frag)
typedef __attribute__((ext_vector_type(8))) unsigned short u16x8;
typedef __attribute__((ext_vector_type(4))) float f32x4;
typedef __attribute__((ext_vector_type(4))) int i32x4;

__device__ __forceinline__ u16 f2bf(float f) {
  uint32_t u = __builtin_bit_cast(uint32_t, f);
  u += 0x7fffu + ((u >> 16) & 1u);   // RNE
  return (u16)(u >> 16);
}

// async global->LDS, 16B per lane; LDS dest must be wave-uniform base (+lane*16 implicit)
#define GLD16(g, l)                                                         \
  __builtin_amdgcn_global_load_lds(                                         \
      (const __attribute__((address_space(1))) void*)(g),                   \
      (__attribute__((address_space(3))) void*)(l), 16, 0, 0)

// ---------------- elementwise prep kernels ----------------

__global__ __launch_bounds__(256) void cvt_f32_bf16(const float* __restrict__ src,
                                                    u16* __restrict__ dst, int n8) {
  int t = blockIdx.x * 256 + threadIdx.x;
  if (t >= n8) return;
  f32x4 a = ((const f32x4*)src)[2 * t];
  f32x4 b = ((const f32x4*)src)[2 * t + 1];
  u16x8 o;
  o[0] = f2bf(a[0]); o[1] = f2bf(a[1]); o[2] = f2bf(a[2]); o[3] = f2bf(a[3]);
  o[4] = f2bf(b[0]); o[5] = f2bf(b[1]); o[6] = f2bf(b[2]); o[7] = f2bf(b[3]);
  ((u16x8*)dst)[t] = o;
}

// q:[O][G][128] int32 (flat == row-major [O][I]), s/z:[O][G] -> w bf16 [O][I]
__global__ __launch_bounds__(256) void dequant_w(const int* __restrict__ q,
                                                 const float* __restrict__ s,
                                                 const float* __restrict__ z,
                                                 u16* __restrict__ w, int n8) {
  int t = blockIdx.x * 256 + threadIdx.x;
  if (t >= n8) return;
  int g = t >> 4;                 // 8 elems/thread, 128 elems/group -> 16 threads/group
  float sc = s[g];
  float zp = z[g];
  i32x4 a = ((const i32x4*)q)[2 * t];
  i32x4 b = ((const i32x4*)q)[2 * t + 1];
  u16x8 o;
  o[0] = f2bf(((float)a[0] - zp) * sc);
  o[1] = f2bf(((float)a[1] - zp) * sc);
  o[2] = f2bf(((float)a[2] - zp) * sc);
  o[3] = f2bf(((float)a[3] - zp) * sc);
  o[4] = f2bf(((float)b[0] - zp) * sc);
  o[5] = f2bf(((float)b[1] - zp) * sc);
  o[6] = f2bf(((float)b[2] - zp) * sc);
  o[7] = f2bf(((float)b[3] - zp) * sc);
  ((u16x8*)w)[t] = o;
}

__global__ __launch_bounds__(256) void bias_init(float* __restrict__ out,
                                                 const float* __restrict__ b,
                                                 int N, int n4) {
  int t = blockIdx.x * 256 + threadIdx.x;
  if (t >= n4) return;
  int idx = t * 4;
  int n = idx & (N - 1);          // N is a power of two (2048)
  *(f32x4*)(out + idx) = *(const f32x4*)(b + n);
}

// ---------------- NT GEMM: C[M,N] = A[M,K] * B[N,K]^T (+bias, relu) ----------------
// 128x128 tile, 4 waves in 2x2, each wave 64x64 via 4x4 MFMA 16x16x32 bf16, BK=32.
template <bool RELU, bool OUT_BF16, bool ATOMIC>
__global__ __launch_bounds__(256) void gemm_bt(const u16* __restrict__ A,
                                               const u16* __restrict__ Bm,
                                               const float* __restrict__ bias,
                                               void* __restrict__ Cout,
                                               int M, int N, int K, int kChunk) {
  __shared__ u16 As[128 * 32];
  __shared__ u16 Bs[128 * 32];
  const int tid = threadIdx.x;
  const int wave = tid >> 6;
  const int lane = tid & 63;
  const int m0 = blockIdx.y << 7;
  const int n0 = blockIdx.x << 7;
  const int kStart = blockIdx.z * kChunk;
  const int srow = lane >> 2;         // staging: 16 rows x 4 lanes*16B = 1024B / issue
  const int scol = (lane & 3) << 3;   // element offset within BK
  const int wm = (wave >> 1) << 6;
  const int wn = (wave & 1) << 6;
  const int quad = lane >> 4;
  const int l15 = lane & 15;

  const u16* Ab = A + (size_t)(m0 + 32 * wave + srow) * K + kStart + scol;
  const u16* Bb = Bm + (size_t)(n0 + 32 * wave + srow) * K + kStart + scol;
  u16* AsD0 = &As[(32 * wave + 0) * 32];
  u16* AsD1 = &As[(32 * wave + 16) * 32];
  u16* BsD0 = &Bs[(32 * wave + 0) * 32];
  u16* BsD1 = &Bs[(32 * wave + 16) * 32];
  const size_t rowskip = (size_t)16 * K;

  f32x4 acc[4][4];
#pragma unroll
  for (int i = 0; i < 4; i++)
#pragma unroll
    for (int j = 0; j < 4; j++) acc[i][j] = (f32x4){0.f, 0.f, 0.f, 0.f};

  for (int k = 0; k < kChunk; k += 32) {
    GLD16(Ab + k, AsD0);
    GLD16(Ab + k + rowskip, AsD1);
    GLD16(Bb + k, BsD0);
    GLD16(Bb + k + rowskip, BsD1);
    __syncthreads();   // drains vmcnt(0) then barrier
    bf16x8 af[4], bf[4];
#pragma unroll
    for (int i = 0; i < 4; i++)
      af[i] = *(const bf16x8*)&As[(wm + i * 16 + l15) * 32 + quad * 8];
#pragma unroll
    for (int j = 0; j < 4; j++)
      bf[j] = *(const bf16x8*)&Bs[(wn + j * 16 + l15) * 32 + quad * 8];
#pragma unroll
    for (int i = 0; i < 4; i++)
#pragma unroll
      for (int j = 0; j < 4; j++)
        acc[i][j] = __builtin_amdgcn_mfma_f32_16x16x32_bf16(af[i], bf[j], acc[i][j], 0, 0, 0);
    __syncthreads();   // protect LDS before next stage
  }

  // epilogue: C/D layout col=lane&15, row=quad*4+reg (verified m89/m91)
#pragma unroll
  for (int i = 0; i < 4; i++) {
#pragma unroll
    for (int j = 0; j < 4; j++) {
      const int col = n0 + wn + j * 16 + l15;
      float bv = 0.f;
      if (!ATOMIC) bv = bias[col];
#pragma unroll
      for (int r = 0; r < 4; r++) {
        const int row = m0 + wm + i * 16 + quad * 4 + r;
        float v = acc[i][j][r];
        if (ATOMIC) {
          atomicAdd((float*)Cout + (size_t)row * N + col, v);
        } else {
          v += bv;
          if (RELU) v = v > 0.f ? v : 0.f;
          if (OUT_BF16)
            ((u16*)Cout)[(size_t)row * N + col] = f2bf(v);
          else
            ((float*)Cout)[(size_t)row * N + col] = v;
        }
      }
    }
  }
}

// ---------------- launch ----------------

extern "C" void kernel_launch(void* const* d_in, const int* in_sizes, int n_in,
                              void* d_out, int out_size, void* d_ws, size_t ws_size,
                              hipStream_t stream) {
  const float* x  = (const float*)d_in[0];
  const int*   q1 = (const int*)d_in[1];
  const float* s1 = (const float*)d_in[2];
  const float* z1 = (const float*)d_in[3];
  const float* b1 = (const float*)d_in[4];
  const int*   q2 = (const int*)d_in[5];
  const float* s2 = (const float*)d_in[6];
  const float* z2 = (const float*)d_in[7];
  const float* b2 = (const float*)d_in[8];
  float* out = (float*)d_out;

  const int B = 512, D_IN = 2048, D_H = 8192, D_OUT = 2048;

  char* ws = (char*)d_ws;
  u16* xb  = (u16*)(ws);                                   //  2 MB: x bf16 [512][2048]
  u16* w1b = (u16*)(ws + (size_t)2 * 1024 * 1024);         // 32 MB: w1 bf16 [8192][2048]
  u16* hb  = (u16*)(ws + (size_t)34 * 1024 * 1024);        //  8 MB: h bf16 [512][8192]
  u16* w2b = (u16*)(ws + (size_t)42 * 1024 * 1024);        // 32 MB: w2 bf16 [2048][8192]

  // 1. x -> bf16
  cvt_f32_bf16<<<(B * D_IN / 8 + 255) / 256, 256, 0, stream>>>(x, xb, B * D_IN / 8);
  // 2. dequant weights -> bf16
  dequant_w<<<(D_H * D_IN / 8 + 255) / 256, 256, 0, stream>>>(q1, s1, z1, w1b, D_H * D_IN / 8);
  dequant_w<<<(D_OUT * D_H / 8 + 255) / 256, 256, 0, stream>>>(q2, s2, z2, w2b, D_OUT * D_H / 8);
  // 3. h = relu(x @ w1^T + b1), bf16 out
  dim3 g1(D_H / 128, B / 128, 1);
  gemm_bt<true, true, false><<<g1, 256, 0, stream>>>(xb, w1b, b1, hb, B, D_H, D_IN, D_IN);
  // 4. out = b2 (broadcast), then split-K=4 atomic accumulate h @ w2^T
  bias_init<<<(B * D_OUT / 4 + 255) / 256, 256, 0, stream>>>(out, b2, D_OUT, B * D_OUT / 4);
  dim3 g2(D_OUT / 128, B / 128, 4);
  gemm_bt<false, false, true><<<g2, 256, 0, stream>>>(hb, w2b, nullptr, out, B, D_OUT, D_H, D_H / 4);
}